// Round 3
// baseline (1363.918 us; speedup 1.0000x reference)
//
#include <hip/hip_runtime.h>

#define NN 50000
#define NE 800000
#define DD 128

typedef unsigned int u32;
typedef unsigned short u16;
typedef unsigned long long u64;

__device__ __forceinline__ float bf2f(u16 u) {
    union { float f; u32 i; } v; v.i = ((u32)u) << 16; return v.f;
}

// K0: detect device dtypes. flags[0]=1 if floats are bf16 (else f32),
// flags[1]=1 if edge_index is int64 (else int32).
__global__ __launch_bounds__(64) void gin_detect(const u32* __restrict__ xw,
                                                 const u32* __restrict__ ew,
                                                 int* __restrict__ flags) {
    int lane = threadIdx.x;  // 0..63
    u32 w = xw[lane];
    u32 e8 = (w >> 7) & 0xFFu;            // exponent field of low bf16 candidate
    bool bfOK = (e8 >= 100u && e8 <= 150u) || ((w & 0xFFFFu) == 0u);
    u64 m1 = __ballot(bfOK);
    bool oddZero = (ew[2 * lane + 1] == 0u);  // int64 high words are 0
    u64 m2 = __ballot(oddZero);
    if (lane == 0) {
        flags[0] = (__popcll(m1) >= 56) ? 1 : 0;
        flags[1] = (__popcll(m2) >= 60) ? 1 : 0;
    }
}

// K1: z = (1+eta) * x   (f32 or bf16 in, f32 out to workspace)
__global__ __launch_bounds__(256) void gin_init(const void* __restrict__ xv,
                                                const void* __restrict__ etav,
                                                float* __restrict__ z,
                                                const int* __restrict__ flags) {
    int i = blockIdx.x * 256 + threadIdx.x;  // index of 8-element group
    const int n8 = NN * DD / 8;
    if (i >= n8) return;
    const int fbf = flags[0];
    float s = 1.0f + (fbf ? bf2f(((const u16*)etav)[0]) : ((const float*)etav)[0]);
    float4 a, b;
    if (fbf) {
        uint4 p = ((const uint4*)xv)[i];
        a.x = bf2f((u16)(p.x & 0xffffu)); a.y = bf2f((u16)(p.x >> 16));
        a.z = bf2f((u16)(p.y & 0xffffu)); a.w = bf2f((u16)(p.y >> 16));
        b.x = bf2f((u16)(p.z & 0xffffu)); b.y = bf2f((u16)(p.z >> 16));
        b.z = bf2f((u16)(p.w & 0xffffu)); b.w = bf2f((u16)(p.w >> 16));
    } else {
        a = ((const float4*)xv)[2 * i + 0];
        b = ((const float4*)xv)[2 * i + 1];
    }
    a.x *= s; a.y *= s; a.z *= s; a.w *= s;
    b.x *= s; b.y *= s; b.z *= s; b.w *= s;
    ((float4*)z)[2 * i + 0] = a;
    ((float4*)z)[2 * i + 1] = b;
}

// K2: scatter-add neighbor features. One wave per edge, lane handles 2 elems.
__global__ __launch_bounds__(256) void gin_scatter(const void* __restrict__ xv,
                                                   const int* __restrict__ ei,
                                                   float* __restrict__ z,
                                                   const int* __restrict__ flags) {
    int e = blockIdx.x * 4 + (threadIdx.x >> 6);
    if (e >= NE) return;
    const int fbf = flags[0];
    const int f64 = flags[1];
    int lane = threadIdx.x & 63;
    int s, d;
    if (f64) {  // int64 little-endian: value in even word
        s = ei[2 * e];
        d = ei[2 * (NE + e)];
    } else {
        s = ei[e];
        d = ei[NE + e];
    }
    float v0, v1;
    if (fbf) {
        u32 p = ((const u32*)((const u16*)xv + (size_t)s * DD))[lane];
        v0 = bf2f((u16)(p & 0xffffu));
        v1 = bf2f((u16)(p >> 16));
    } else {
        float2 p = ((const float2*)((const float*)xv + (size_t)s * DD))[lane];
        v0 = p.x; v1 = p.y;
    }
    float* dst = z + (size_t)d * DD + 2 * lane;
    atomicAdd(dst + 0, v0);
    atomicAdd(dst + 1, v1);
}

// K3: fused MLP (Linear-ReLU-Linear-ReLU) + LayerNorm + skip. Output f32.
#define TR 32
#define NT ((NN + TR - 1) / TR)

__global__ __launch_bounds__(256, 1) void gin_mlp(
    const float* __restrict__ z, const void* __restrict__ x0,
    const void* __restrict__ W1, const void* __restrict__ b1,
    const void* __restrict__ W2, const void* __restrict__ b2,
    const void* __restrict__ gamma, const void* __restrict__ beta,
    float* __restrict__ out, const int* __restrict__ flags) {
    __shared__ float w1t[DD * DD];  // [k][j]
    __shared__ float w2t[DD * DD];
    __shared__ float tile[TR * DD];

    const int tid = threadIdx.x;
    const int fbf = flags[0];

    // stage transposed weights (once per block)
    if (fbf) {
        for (int q = 0; q < 8; ++q) {          // 2048 uint4 (8 bf16 each)
            int idx = tid + q * 256;
            int j = idx >> 4;
            int k = (idx << 3) & 127;
            uint4 a = ((const uint4*)W1)[idx];
            uint4 c = ((const uint4*)W2)[idx];
            u32 aw[4] = {a.x, a.y, a.z, a.w};
            u32 cw[4] = {c.x, c.y, c.z, c.w};
#pragma unroll
            for (int t = 0; t < 4; ++t) {
                w1t[(k + 2 * t + 0) * DD + j] = bf2f((u16)(aw[t] & 0xffffu));
                w1t[(k + 2 * t + 1) * DD + j] = bf2f((u16)(aw[t] >> 16));
                w2t[(k + 2 * t + 0) * DD + j] = bf2f((u16)(cw[t] & 0xffffu));
                w2t[(k + 2 * t + 1) * DD + j] = bf2f((u16)(cw[t] >> 16));
            }
        }
    } else {
        for (int q = 0; q < 16; ++q) {         // 4096 float4
            int idx = tid + q * 256;
            int j = idx >> 5;
            int k = (idx << 2) & 127;
            float4 a = ((const float4*)W1)[idx];
            float4 c = ((const float4*)W2)[idx];
            w1t[(k + 0) * DD + j] = a.x; w1t[(k + 1) * DD + j] = a.y;
            w1t[(k + 2) * DD + j] = a.z; w1t[(k + 3) * DD + j] = a.w;
            w2t[(k + 0) * DD + j] = c.x; w2t[(k + 1) * DD + j] = c.y;
            w2t[(k + 2) * DD + j] = c.z; w2t[(k + 3) * DD + j] = c.w;
        }
    }

    const int lane = tid & 63;
    const int wid = tid >> 6;
    const int jq = lane & 31;      // output quad: j = 4*jq + i
    const int hv = lane >> 5;
    const int lr0 = wid * 8 + hv * 4;

    float b1v[4], b2v[4], gv[4], bev[4];
    if (fbf) {
        uint2 pb1 = ((const uint2*)b1)[jq];
        uint2 pb2 = ((const uint2*)b2)[jq];
        uint2 pg = ((const uint2*)gamma)[jq];
        uint2 pe = ((const uint2*)beta)[jq];
        b1v[0] = bf2f((u16)(pb1.x & 0xffffu)); b1v[1] = bf2f((u16)(pb1.x >> 16));
        b1v[2] = bf2f((u16)(pb1.y & 0xffffu)); b1v[3] = bf2f((u16)(pb1.y >> 16));
        b2v[0] = bf2f((u16)(pb2.x & 0xffffu)); b2v[1] = bf2f((u16)(pb2.x >> 16));
        b2v[2] = bf2f((u16)(pb2.y & 0xffffu)); b2v[3] = bf2f((u16)(pb2.y >> 16));
        gv[0] = bf2f((u16)(pg.x & 0xffffu)); gv[1] = bf2f((u16)(pg.x >> 16));
        gv[2] = bf2f((u16)(pg.y & 0xffffu)); gv[3] = bf2f((u16)(pg.y >> 16));
        bev[0] = bf2f((u16)(pe.x & 0xffffu)); bev[1] = bf2f((u16)(pe.x >> 16));
        bev[2] = bf2f((u16)(pe.y & 0xffffu)); bev[3] = bf2f((u16)(pe.y >> 16));
    } else {
        float4 t1 = ((const float4*)b1)[jq];
        float4 t2 = ((const float4*)b2)[jq];
        float4 t3 = ((const float4*)gamma)[jq];
        float4 t4 = ((const float4*)beta)[jq];
        b1v[0] = t1.x; b1v[1] = t1.y; b1v[2] = t1.z; b1v[3] = t1.w;
        b2v[0] = t2.x; b2v[1] = t2.y; b2v[2] = t2.z; b2v[3] = t2.w;
        gv[0] = t3.x; gv[1] = t3.y; gv[2] = t3.z; gv[3] = t3.w;
        bev[0] = t4.x; bev[1] = t4.y; bev[2] = t4.z; bev[3] = t4.w;
    }

    for (int t = blockIdx.x; t < NT; t += gridDim.x) {
        const int row0 = t * TR;
        __syncthreads();  // protect tile (prev iter readers done)
#pragma unroll
        for (int q = 0; q < 4; ++q) {
            int idx = tid + q * 256;
            int lr = idx >> 5;
            int grow = row0 + lr;
            float4 v;
            if (grow < NN)
                v = ((const float4*)z)[(size_t)grow * (DD / 4) + (idx & 31)];
            else
                v = float4{0.f, 0.f, 0.f, 0.f};
            ((float4*)tile)[idx] = v;
        }
        __syncthreads();

        float acc[4][4];
        // ---- layer 1 ----
#pragma unroll
        for (int r = 0; r < 4; ++r) {
            acc[r][0] = b1v[0]; acc[r][1] = b1v[1];
            acc[r][2] = b1v[2]; acc[r][3] = b1v[3];
        }
        for (int k0 = 0; k0 < DD; k0 += 4) {
            float4 zv[4];
#pragma unroll
            for (int r = 0; r < 4; ++r)
                zv[r] = *(const float4*)&tile[(lr0 + r) * DD + k0];
#pragma unroll
            for (int kk = 0; kk < 4; ++kk) {
                float4 w4 = *(const float4*)&w1t[(k0 + kk) * DD + 4 * jq];
#pragma unroll
                for (int r = 0; r < 4; ++r) {
                    float zz = kk == 0 ? zv[r].x : kk == 1 ? zv[r].y
                              : kk == 2 ? zv[r].z : zv[r].w;
                    acc[r][0] += zz * w4.x;
                    acc[r][1] += zz * w4.y;
                    acc[r][2] += zz * w4.z;
                    acc[r][3] += zz * w4.w;
                }
            }
        }
        __syncthreads();
#pragma unroll
        for (int r = 0; r < 4; ++r) {
            float4 h;
            h.x = fmaxf(acc[r][0], 0.f);
            h.y = fmaxf(acc[r][1], 0.f);
            h.z = fmaxf(acc[r][2], 0.f);
            h.w = fmaxf(acc[r][3], 0.f);
            *(float4*)&tile[(lr0 + r) * DD + 4 * jq] = h;
        }
        __syncthreads();
        // ---- layer 2 ----
#pragma unroll
        for (int r = 0; r < 4; ++r) {
            acc[r][0] = b2v[0]; acc[r][1] = b2v[1];
            acc[r][2] = b2v[2]; acc[r][3] = b2v[3];
        }
        for (int k0 = 0; k0 < DD; k0 += 4) {
            float4 zv[4];
#pragma unroll
            for (int r = 0; r < 4; ++r)
                zv[r] = *(const float4*)&tile[(lr0 + r) * DD + k0];
#pragma unroll
            for (int kk = 0; kk < 4; ++kk) {
                float4 w4 = *(const float4*)&w2t[(k0 + kk) * DD + 4 * jq];
#pragma unroll
                for (int r = 0; r < 4; ++r) {
                    float zz = kk == 0 ? zv[r].x : kk == 1 ? zv[r].y
                              : kk == 2 ? zv[r].z : zv[r].w;
                    acc[r][0] += zz * w4.x;
                    acc[r][1] += zz * w4.y;
                    acc[r][2] += zz * w4.z;
                    acc[r][3] += zz * w4.w;
                }
            }
        }
        // ---- relu + LN + skip + store (f32) ----
#pragma unroll
        for (int r = 0; r < 4; ++r) {
            float h0 = fmaxf(acc[r][0], 0.f);
            float h1 = fmaxf(acc[r][1], 0.f);
            float h2 = fmaxf(acc[r][2], 0.f);
            float h3 = fmaxf(acc[r][3], 0.f);
            float s1 = h0 + h1 + h2 + h3;
            float s2 = h0 * h0 + h1 * h1 + h2 * h2 + h3 * h3;
#pragma unroll
            for (int m = 1; m <= 16; m <<= 1) {
                s1 += __shfl_xor(s1, m);
                s2 += __shfl_xor(s2, m);
            }
            float mean = s1 * (1.0f / DD);
            float var = s2 * (1.0f / DD) - mean * mean;
            float rs = rsqrtf(var + 1e-5f);
            int grow = row0 + lr0 + r;
            if (grow < NN) {
                float xi[4];
                if (fbf) {
                    uint2 px = ((const uint2*)((const u16*)x0 + (size_t)grow * DD))[jq];
                    xi[0] = bf2f((u16)(px.x & 0xffffu)); xi[1] = bf2f((u16)(px.x >> 16));
                    xi[2] = bf2f((u16)(px.y & 0xffffu)); xi[3] = bf2f((u16)(px.y >> 16));
                } else {
                    float4 px = ((const float4*)((const float*)x0 + (size_t)grow * DD))[jq];
                    xi[0] = px.x; xi[1] = px.y; xi[2] = px.z; xi[3] = px.w;
                }
                float4 o;
                o.x = (h0 - mean) * rs * gv[0] + bev[0] + xi[0];
                o.y = (h1 - mean) * rs * gv[1] + bev[1] + xi[1];
                o.z = (h2 - mean) * rs * gv[2] + bev[2] + xi[2];
                o.w = (h3 - mean) * rs * gv[3] + bev[3] + xi[3];
                ((float4*)(out + (size_t)grow * DD))[jq] = o;
            }
        }
    }
}

extern "C" void kernel_launch(void* const* d_in, const int* in_sizes, int n_in,
                              void* d_out, int out_size, void* d_ws, size_t ws_size,
                              hipStream_t stream) {
    const void* x = d_in[0];
    const int* ei = (const int*)d_in[1];
    const void* W1 = d_in[2];
    const void* b1 = d_in[3];
    const void* W2 = d_in[4];
    const void* b2 = d_in[5];
    const void* eta = d_in[6];
    const void* gamma = d_in[7];
    const void* beta = d_in[8];
    float* out = (float*)d_out;

    const size_t zbytes = (size_t)NN * DD * sizeof(float);
    if (ws_size < zbytes + 64) return;
    float* z = (float*)d_ws;
    int* flags = (int*)((char*)d_ws + zbytes);

    gin_detect<<<1, 64, 0, stream>>>((const u32*)x, (const u32*)ei, flags);
    gin_init<<<(NN * DD / 8 + 255) / 256, 256, 0, stream>>>(x, eta, z, flags);
    gin_scatter<<<NE / 4, 256, 0, stream>>>(x, ei, z, flags);
    gin_mlp<<<256, 256, 0, stream>>>(z, x, W1, b1, W2, b2, gamma, beta, out, flags);
}

// Round 4
// 387.602 us; speedup vs baseline: 3.5189x; 3.5189x over previous
//
#include <hip/hip_runtime.h>

#define NN 50000
#define NE 800000
#define DD 128

typedef unsigned int u32;
typedef unsigned short u16;
typedef unsigned long long u64;

__device__ __forceinline__ float bf2f(u16 u) {
    union { float f; u32 i; } v; v.i = ((u32)u) << 16; return v.f;
}

// ---------------- K0: dtype detect ----------------
// flags[0]=1 if float data is bf16 (else f32); flags[1]=1 if edge_index int64.
__global__ __launch_bounds__(64) void gin_detect(const u32* __restrict__ xw,
                                                 const u32* __restrict__ ew,
                                                 int* __restrict__ flags) {
    int lane = threadIdx.x;
    u32 w = xw[lane];
    u32 e8 = (w >> 7) & 0xFFu;
    bool bfOK = (e8 >= 100u && e8 <= 150u) || ((w & 0xFFFFu) == 0u);
    u64 m1 = __ballot(bfOK);
    bool oddZero = (ew[2 * lane + 1] == 0u);
    u64 m2 = __ballot(oddZero);
    if (lane == 0) {
        flags[0] = (__popcll(m1) >= 56) ? 1 : 0;
        flags[1] = (__popcll(m2) >= 60) ? 1 : 0;
    }
}

// ---------------- CSR build ----------------
__global__ __launch_bounds__(256) void gin_zero(u32* __restrict__ deg) {
    int i = blockIdx.x * 256 + threadIdx.x;
    if (i < NN) deg[i] = 0u;
}

__global__ __launch_bounds__(256) void gin_hist(const int* __restrict__ ei,
                                                u32* __restrict__ deg,
                                                const int* __restrict__ flags) {
    int e = blockIdx.x * 256 + threadIdx.x;
    if (e >= NE) return;
    int d = flags[1] ? ei[2 * (NE + e)] : ei[NE + e];
    atomicAdd(&deg[d], 1u);
}

__global__ __launch_bounds__(1024) void gin_scan(const u32* __restrict__ deg,
                                                 u32* __restrict__ row_start,
                                                 u32* __restrict__ cursor) {
    __shared__ u32 part[1024];
    const int tid = threadIdx.x;
    const int CH = (NN + 1023) / 1024;  // 49
    int b = tid * CH;
    int e = b + CH; if (e > NN) e = NN;
    u32 s = 0;
    for (int i = b; i < e; ++i) s += deg[i];
    part[tid] = s;
    __syncthreads();
    for (int off = 1; off < 1024; off <<= 1) {
        u32 v = (tid >= off) ? part[tid - off] : 0u;
        __syncthreads();
        part[tid] += v;
        __syncthreads();
    }
    u32 run = (tid == 0) ? 0u : part[tid - 1];
    for (int i = b; i < e; ++i) {
        row_start[i] = run;
        cursor[i] = run;
        run += deg[i];
    }
    if (tid == 1023) row_start[NN] = run;
}

__global__ __launch_bounds__(256) void gin_fill(const int* __restrict__ ei,
                                                u32* __restrict__ cursor,
                                                u32* __restrict__ bs,
                                                const int* __restrict__ flags) {
    int e = blockIdx.x * 256 + threadIdx.x;
    if (e >= NE) return;
    int s, d;
    if (flags[1]) { s = ei[2 * e]; d = ei[2 * (NE + e)]; }
    else          { s = ei[e];     d = ei[NE + e]; }
    u32 pos = atomicAdd(&cursor[d], 1u);
    bs[pos] = (u32)s;
}

// ---------------- gather-sum (+init) : z = (1+eta)x + sum_{src->n} x[src] ----
__global__ __launch_bounds__(256) void gin_gather(const void* __restrict__ xv,
                                                  const u32* __restrict__ bs,
                                                  const u32* __restrict__ row_start,
                                                  const u32* __restrict__ row_end,
                                                  const void* __restrict__ etav,
                                                  float* __restrict__ z,
                                                  const int* __restrict__ flags) {
    int node = blockIdx.x * 4 + (threadIdx.x >> 6);
    if (node >= NN) return;
    const int lane = threadIdx.x & 63;
    const int fbf = flags[0];
    float s = 1.0f + (fbf ? bf2f(((const u16*)etav)[0]) : ((const float*)etav)[0]);
    float ax, ay;
    if (fbf) {
        u32 p = ((const u32*)((const u16*)xv + (size_t)node * DD))[lane];
        ax = bf2f((u16)(p & 0xffffu)) * s;
        ay = bf2f((u16)(p >> 16)) * s;
    } else {
        float2 p = ((const float2*)((const float*)xv + (size_t)node * DD))[lane];
        ax = p.x * s; ay = p.y * s;
    }
    u32 jb = row_start[node], je = row_end[node];
    if (fbf) {
        for (u32 j = jb; j < je; ++j) {
            u32 src = bs[j];
            u32 p = ((const u32*)((const u16*)xv + (size_t)src * DD))[lane];
            ax += bf2f((u16)(p & 0xffffu));
            ay += bf2f((u16)(p >> 16));
        }
    } else {
        for (u32 j = jb; j < je; ++j) {
            u32 src = bs[j];
            float2 p = ((const float2*)((const float*)xv + (size_t)src * DD))[lane];
            ax += p.x; ay += p.y;
        }
    }
    float2 o; o.x = ax; o.y = ay;
    ((float2*)(z + (size_t)node * DD))[lane] = o;
}

// ---------------- fallback: init + atomic scatter (if ws too small) ---------
__global__ __launch_bounds__(256) void gin_init(const void* __restrict__ xv,
                                                const void* __restrict__ etav,
                                                float* __restrict__ z,
                                                const int* __restrict__ flags) {
    int i = blockIdx.x * 256 + threadIdx.x;
    const int n8 = NN * DD / 8;
    if (i >= n8) return;
    const int fbf = flags[0];
    float s = 1.0f + (fbf ? bf2f(((const u16*)etav)[0]) : ((const float*)etav)[0]);
    float4 a, b;
    if (fbf) {
        uint4 p = ((const uint4*)xv)[i];
        a.x = bf2f((u16)(p.x & 0xffffu)); a.y = bf2f((u16)(p.x >> 16));
        a.z = bf2f((u16)(p.y & 0xffffu)); a.w = bf2f((u16)(p.y >> 16));
        b.x = bf2f((u16)(p.z & 0xffffu)); b.y = bf2f((u16)(p.z >> 16));
        b.z = bf2f((u16)(p.w & 0xffffu)); b.w = bf2f((u16)(p.w >> 16));
    } else {
        a = ((const float4*)xv)[2 * i + 0];
        b = ((const float4*)xv)[2 * i + 1];
    }
    a.x *= s; a.y *= s; a.z *= s; a.w *= s;
    b.x *= s; b.y *= s; b.z *= s; b.w *= s;
    ((float4*)z)[2 * i + 0] = a;
    ((float4*)z)[2 * i + 1] = b;
}

__global__ __launch_bounds__(256) void gin_scatter(const void* __restrict__ xv,
                                                   const int* __restrict__ ei,
                                                   float* __restrict__ z,
                                                   const int* __restrict__ flags) {
    int e = blockIdx.x * 4 + (threadIdx.x >> 6);
    if (e >= NE) return;
    const int fbf = flags[0];
    const int f64 = flags[1];
    int lane = threadIdx.x & 63;
    int s, d;
    if (f64) { s = ei[2 * e]; d = ei[2 * (NE + e)]; }
    else     { s = ei[e];     d = ei[NE + e]; }
    float v0, v1;
    if (fbf) {
        u32 p = ((const u32*)((const u16*)xv + (size_t)s * DD))[lane];
        v0 = bf2f((u16)(p & 0xffffu));
        v1 = bf2f((u16)(p >> 16));
    } else {
        float2 p = ((const float2*)((const float*)xv + (size_t)s * DD))[lane];
        v0 = p.x; v1 = p.y;
    }
    float* dst = z + (size_t)d * DD + 2 * lane;
    atomicAdd(dst + 0, v0);
    atomicAdd(dst + 1, v1);
}

// ---------------- fused MLP + LN + skip (template on dtype) ----------------
#define TRM 64   // rows per tile
#define NTM ((NN + TRM - 1) / TRM)

template <int FBF>
__global__ __launch_bounds__(512, 1) void gin_mlp(
    const float* __restrict__ z, const void* __restrict__ x0,
    const void* __restrict__ W1, const void* __restrict__ b1,
    const void* __restrict__ W2, const void* __restrict__ b2,
    const void* __restrict__ gamma, const void* __restrict__ beta,
    float* __restrict__ out, const int* __restrict__ flags) {
    if (flags[0] != FBF) return;  // wave-uniform early exit (dud variant)

    __shared__ float w1t[DD * DD];   // 64 KB, [k][j]
    __shared__ float w2t[DD * DD];   // 64 KB
    __shared__ float tile[TRM * DD]; // 32 KB

    const int tid = threadIdx.x;

    // ---- stage transposed weights (once per block) ----
    if (FBF) {
        for (int q = 0; q < 4; ++q) {            // 2048 uint4 per matrix
            int idx = tid + q * 512;
            int j = idx >> 4;                    // 16 uint4 per row
            int k = (idx & 15) * 8;
            uint4 a = ((const uint4*)W1)[idx];
            uint4 c = ((const uint4*)W2)[idx];
            u32 aw[4] = {a.x, a.y, a.z, a.w};
            u32 cw[4] = {c.x, c.y, c.z, c.w};
#pragma unroll
            for (int t = 0; t < 4; ++t) {
                w1t[(k + 2 * t + 0) * DD + j] = bf2f((u16)(aw[t] & 0xffffu));
                w1t[(k + 2 * t + 1) * DD + j] = bf2f((u16)(aw[t] >> 16));
                w2t[(k + 2 * t + 0) * DD + j] = bf2f((u16)(cw[t] & 0xffffu));
                w2t[(k + 2 * t + 1) * DD + j] = bf2f((u16)(cw[t] >> 16));
            }
        }
    } else {
        for (int q = 0; q < 8; ++q) {            // 4096 float4 per matrix
            int idx = tid + q * 512;
            int j = idx >> 5;                    // 32 float4 per row
            int k = (idx & 31) * 4;
            float4 a = ((const float4*)W1)[idx];
            float4 c = ((const float4*)W2)[idx];
            w1t[(k + 0) * DD + j] = a.x; w1t[(k + 1) * DD + j] = a.y;
            w1t[(k + 2) * DD + j] = a.z; w1t[(k + 3) * DD + j] = a.w;
            w2t[(k + 0) * DD + j] = c.x; w2t[(k + 1) * DD + j] = c.y;
            w2t[(k + 2) * DD + j] = c.z; w2t[(k + 3) * DD + j] = c.w;
        }
    }

    const int cg = tid & 31;        // col group: j0 = 4*cg
    const int rg = tid >> 5;        // row group: r0 = 4*rg (0..15)
    const int j0 = cg * 4;
    const int r0 = rg * 4;

    float b1v[4], b2v[4], gv[4], bev[4];
    if (FBF) {
        uint2 pb1 = ((const uint2*)b1)[cg];
        uint2 pb2 = ((const uint2*)b2)[cg];
        uint2 pg = ((const uint2*)gamma)[cg];
        uint2 pe = ((const uint2*)beta)[cg];
        b1v[0] = bf2f((u16)(pb1.x & 0xffffu)); b1v[1] = bf2f((u16)(pb1.x >> 16));
        b1v[2] = bf2f((u16)(pb1.y & 0xffffu)); b1v[3] = bf2f((u16)(pb1.y >> 16));
        b2v[0] = bf2f((u16)(pb2.x & 0xffffu)); b2v[1] = bf2f((u16)(pb2.x >> 16));
        b2v[2] = bf2f((u16)(pb2.y & 0xffffu)); b2v[3] = bf2f((u16)(pb2.y >> 16));
        gv[0] = bf2f((u16)(pg.x & 0xffffu)); gv[1] = bf2f((u16)(pg.x >> 16));
        gv[2] = bf2f((u16)(pg.y & 0xffffu)); gv[3] = bf2f((u16)(pg.y >> 16));
        bev[0] = bf2f((u16)(pe.x & 0xffffu)); bev[1] = bf2f((u16)(pe.x >> 16));
        bev[2] = bf2f((u16)(pe.y & 0xffffu)); bev[3] = bf2f((u16)(pe.y >> 16));
    } else {
        float4 t1 = ((const float4*)b1)[cg];
        float4 t2 = ((const float4*)b2)[cg];
        float4 t3 = ((const float4*)gamma)[cg];
        float4 t4 = ((const float4*)beta)[cg];
        b1v[0] = t1.x; b1v[1] = t1.y; b1v[2] = t1.z; b1v[3] = t1.w;
        b2v[0] = t2.x; b2v[1] = t2.y; b2v[2] = t2.z; b2v[3] = t2.w;
        gv[0] = t3.x; gv[1] = t3.y; gv[2] = t3.z; gv[3] = t3.w;
        bev[0] = t4.x; bev[1] = t4.y; bev[2] = t4.z; bev[3] = t4.w;
    }

    for (int t = blockIdx.x; t < NTM; t += gridDim.x) {
        const int row0 = t * TRM;
        __syncthreads();  // previous iteration's readers done
        // stage z tile: TRM*DD floats = 2048 float4, 4 per thread
#pragma unroll
        for (int q = 0; q < 4; ++q) {
            int idx = tid + q * 512;
            int lr = idx >> 5;
            int grow = row0 + lr;
            float4 v;
            if (grow < NN)
                v = ((const float4*)z)[(size_t)grow * (DD / 4) + (idx & 31)];
            else
                v = float4{0.f, 0.f, 0.f, 0.f};
            ((float4*)tile)[idx] = v;
        }
        __syncthreads();

        float acc[4][4];
        // ---- layer 1 ----
#pragma unroll
        for (int r = 0; r < 4; ++r) {
            acc[r][0] = b1v[0]; acc[r][1] = b1v[1];
            acc[r][2] = b1v[2]; acc[r][3] = b1v[3];
        }
        for (int k0 = 0; k0 < DD; k0 += 4) {
#pragma unroll
            for (int kk = 0; kk < 4; ++kk) {
                float4 w4 = *(const float4*)&w1t[(k0 + kk) * DD + j0];
#pragma unroll
                for (int r = 0; r < 4; ++r) {
                    float zz = tile[(r0 + r) * DD + k0 + kk];
                    acc[r][0] += zz * w4.x;
                    acc[r][1] += zz * w4.y;
                    acc[r][2] += zz * w4.z;
                    acc[r][3] += zz * w4.w;
                }
            }
        }
        __syncthreads();
#pragma unroll
        for (int r = 0; r < 4; ++r) {
            float4 h;
            h.x = fmaxf(acc[r][0], 0.f);
            h.y = fmaxf(acc[r][1], 0.f);
            h.z = fmaxf(acc[r][2], 0.f);
            h.w = fmaxf(acc[r][3], 0.f);
            *(float4*)&tile[(r0 + r) * DD + j0] = h;
        }
        __syncthreads();
        // ---- layer 2 ----
#pragma unroll
        for (int r = 0; r < 4; ++r) {
            acc[r][0] = b2v[0]; acc[r][1] = b2v[1];
            acc[r][2] = b2v[2]; acc[r][3] = b2v[3];
        }
        for (int k0 = 0; k0 < DD; k0 += 4) {
#pragma unroll
            for (int kk = 0; kk < 4; ++kk) {
                float4 w4 = *(const float4*)&w2t[(k0 + kk) * DD + j0];
#pragma unroll
                for (int r = 0; r < 4; ++r) {
                    float zz = tile[(r0 + r) * DD + k0 + kk];
                    acc[r][0] += zz * w4.x;
                    acc[r][1] += zz * w4.y;
                    acc[r][2] += zz * w4.z;
                    acc[r][3] += zz * w4.w;
                }
            }
        }
        // ---- relu + LN + skip + store ----
#pragma unroll
        for (int r = 0; r < 4; ++r) {
            float h0 = fmaxf(acc[r][0], 0.f);
            float h1 = fmaxf(acc[r][1], 0.f);
            float h2 = fmaxf(acc[r][2], 0.f);
            float h3 = fmaxf(acc[r][3], 0.f);
            float s1 = h0 + h1 + h2 + h3;
            float s2 = h0 * h0 + h1 * h1 + h2 * h2 + h3 * h3;
#pragma unroll
            for (int m = 1; m <= 16; m <<= 1) {
                s1 += __shfl_xor(s1, m);
                s2 += __shfl_xor(s2, m);
            }
            float mean = s1 * (1.0f / DD);
            float var = s2 * (1.0f / DD) - mean * mean;
            float rs = rsqrtf(var + 1e-5f);
            int grow = row0 + r0 + r;
            if (grow < NN) {
                float xi[4];
                if (FBF) {
                    uint2 px = ((const uint2*)((const u16*)x0 + (size_t)grow * DD))[cg];
                    xi[0] = bf2f((u16)(px.x & 0xffffu)); xi[1] = bf2f((u16)(px.x >> 16));
                    xi[2] = bf2f((u16)(px.y & 0xffffu)); xi[3] = bf2f((u16)(px.y >> 16));
                } else {
                    float4 px = ((const float4*)((const float*)x0 + (size_t)grow * DD))[cg];
                    xi[0] = px.x; xi[1] = px.y; xi[2] = px.z; xi[3] = px.w;
                }
                float4 o;
                o.x = (h0 - mean) * rs * gv[0] + bev[0] + xi[0];
                o.y = (h1 - mean) * rs * gv[1] + bev[1] + xi[1];
                o.z = (h2 - mean) * rs * gv[2] + bev[2] + xi[2];
                o.w = (h3 - mean) * rs * gv[3] + bev[3] + xi[3];
                ((float4*)(out + (size_t)grow * DD))[cg] = o;
            }
        }
    }
}

extern "C" void kernel_launch(void* const* d_in, const int* in_sizes, int n_in,
                              void* d_out, int out_size, void* d_ws, size_t ws_size,
                              hipStream_t stream) {
    const void* x = d_in[0];
    const int* ei = (const int*)d_in[1];
    const void* W1 = d_in[2];
    const void* b1 = d_in[3];
    const void* W2 = d_in[4];
    const void* b2 = d_in[5];
    const void* eta = d_in[6];
    const void* gamma = d_in[7];
    const void* beta = d_in[8];
    float* out = (float*)d_out;

    // workspace layout (256B aligned)
    const size_t FLAGS_OFF = 0;
    const size_t Z_OFF = 256;
    const size_t ZB = (size_t)NN * DD * sizeof(float);  // 25,600,000
    const size_t DEG_OFF = Z_OFF + ZB;
    const size_t DEGB = 200192;                          // NN u32, padded
    const size_t RS_OFF = DEG_OFF + DEGB;
    const size_t RSB = 200448;                           // NN+1 u32, padded
    const size_t BS_OFF = RS_OFF + RSB;
    const size_t BSB = (size_t)NE * sizeof(u32);         // 3,200,000
    const size_t TOT = BS_OFF + BSB;                     // ~29.2 MB

    if (ws_size < Z_OFF + ZB) return;
    int* flags = (int*)((char*)d_ws + FLAGS_OFF);
    float* z = (float*)((char*)d_ws + Z_OFF);

    gin_detect<<<1, 64, 0, stream>>>((const u32*)x, (const u32*)ei, flags);

    if (ws_size >= TOT) {
        u32* deg = (u32*)((char*)d_ws + DEG_OFF);       // becomes cursor/row_end
        u32* row_start = (u32*)((char*)d_ws + RS_OFF);
        u32* bs = (u32*)((char*)d_ws + BS_OFF);
        gin_zero<<<(NN + 255) / 256, 256, 0, stream>>>(deg);
        gin_hist<<<(NE + 255) / 256, 256, 0, stream>>>(ei, deg, flags);
        // scan reads deg, writes row_start and resets deg as cursor
        gin_scan<<<1, 1024, 0, stream>>>(deg, row_start, deg);
        gin_fill<<<(NE + 255) / 256, 256, 0, stream>>>(ei, deg, bs, flags);
        // after fill: deg[n] == row_end[n]
        gin_gather<<<(NN + 3) / 4, 256, 0, stream>>>(x, bs, row_start, deg, eta, z, flags);
    } else {
        gin_init<<<(NN * DD / 8 + 255) / 256, 256, 0, stream>>>(x, eta, z, flags);
        gin_scatter<<<NE / 4, 256, 0, stream>>>(x, ei, z, flags);
    }

    gin_mlp<0><<<256, 512, 0, stream>>>(z, x, W1, b1, W2, b2, gamma, beta, out, flags);
    gin_mlp<1><<<256, 512, 0, stream>>>(z, x, W1, b1, W2, b2, gamma, beta, out, flags);
}